// Round 5
// baseline (923.354 us; speedup 1.0000x reference)
//
#include <hip/hip_runtime.h>
#include <hip/hip_bf16.h>
#include <math.h>

constexpr int NN = 50000;   // nodes
constexpr int NE = 800000;  // edges (without self loops)
constexpr int NH = 8;       // heads
constexpr float L2E = 1.44269504f;  // log2(e)

typedef __attribute__((ext_vector_type(8))) short bf16x8;
typedef __attribute__((ext_vector_type(4))) float f32x4;

__device__ inline float b2f(unsigned short u) {
  union { unsigned int i; float f; } v;
  v.i = ((unsigned int)u) << 16;
  return v.f;
}

// ---------------------------------------------------------------------------
// degree histograms (real edges only; self-loop handled in epilogues)
__global__ void k_deg(const int* __restrict__ src, const int* __restrict__ dst,
                      int* __restrict__ degout, int* __restrict__ degin) {
  int i = blockIdx.x * blockDim.x + threadIdx.x;
  if (i < NE) {
    atomicAdd(&degout[src[i]], 1);
    atomicAdd(&degin[dst[i]], 1);
  }
}

__global__ void k_inv(const int* __restrict__ degin, float* __restrict__ inv) {
  int i = blockIdx.x * blockDim.x + threadIdx.x;
  if (i < NN) inv[i] = 1.0f / (float)(degin[i] + 1);
}

// single-block exclusive scan of degout -> base (also cursor = base)
__global__ void __launch_bounds__(1024) k_scan(const int* __restrict__ deg,
                                               int* __restrict__ base,
                                               int* __restrict__ cursor) {
  __shared__ int ls[1024];
  const int t = threadIdx.x;
  const int CHK = (NN + 1023) / 1024;  // 49
  const int start = t * CHK;
  int s = 0;
  for (int i = 0; i < CHK; ++i) {
    int idx = start + i;
    if (idx < NN) s += deg[idx];
  }
  ls[t] = s;
  __syncthreads();
  for (int off = 1; off < 1024; off <<= 1) {
    int v = (t >= off) ? ls[t - off] : 0;
    __syncthreads();
    ls[t] += v;
    __syncthreads();
  }
  int prefix = ls[t] - s;  // exclusive prefix for this chunk
  for (int i = 0; i < CHK; ++i) {
    int idx = start + i;
    if (idx < NN) {
      base[idx] = prefix;
      cursor[idx] = prefix;
      prefix += deg[idx];
    }
  }
}

// scatter: csr2[pos] = (dst, src), grouped by src. cursor[n] ends at range end.
__global__ void k_scatter(const int* __restrict__ src, const int* __restrict__ dst,
                          int* __restrict__ cursor, int2* __restrict__ csr2) {
  int e = blockIdx.x * blockDim.x + threadIdx.x;
  if (e < NE) {
    int s = src[e];
    int pos = atomicAdd(&cursor[s], 1);
    csr2[pos] = make_int2(dst[e], s);
  }
}

// ---------------------------------------------------------------------------
// fp32 -> bf16 conversion, 4 elements/thread
__global__ void k_f2b(const float* __restrict__ in, __hip_bfloat16* __restrict__ out,
                      long n4) {
  long i = (long)blockIdx.x * blockDim.x + threadIdx.x;
  if (i >= n4) return;
  float4 v = reinterpret_cast<const float4*>(in)[i];
  ushort4 o;
  o.x = __hip_bfloat16_raw(__float2bfloat16(v.x)).x;
  o.y = __hip_bfloat16_raw(__float2bfloat16(v.y)).x;
  o.z = __hip_bfloat16_raw(__float2bfloat16(v.z)).x;
  o.w = __hip_bfloat16_raw(__float2bfloat16(v.w)).x;
  reinterpret_cast<ushort4*>(out)[i] = o;
}

// ---------------------------------------------------------------------------
// q[n,h] = log2(e) * sum_c X[n,c] * U[h,c]   (prescaled for raw v_exp_f32)
__global__ void k_q(const float* __restrict__ X, const float* __restrict__ U,
                    float* __restrict__ q) {
  int n = blockIdx.x * blockDim.x + threadIdx.x;
  if (n >= NN) return;
  float4 xr[16];
  const float4* X4 = reinterpret_cast<const float4*>(X) + (size_t)n * 16;
#pragma unroll
  for (int i = 0; i < 16; ++i) xr[i] = X4[i];
  const float4* U4 = reinterpret_cast<const float4*>(U);
#pragma unroll
  for (int h = 0; h < 8; ++h) {
    float a = 0.f;
#pragma unroll
    for (int i = 0; i < 16; ++i) {
      float4 u = U4[h * 16 + i];
      a = fmaf(xr[i].x, u.x, a);
      a = fmaf(xr[i].y, u.y, a);
      a = fmaf(xr[i].z, u.z, a);
      a = fmaf(xr[i].w, u.w, a);
    }
    q[(size_t)n * 8 + h] = a * L2E;
  }
}

// ---------------------------------------------------------------------------
// P[n, j] = sum_c Xb[n,c] * Wb[j,c]  via MFMA bf16 (K=64 -> 2 k-steps of 32)
template <int JDIM>
__global__ void __launch_bounds__(JDIM / 64 * 64)
k_mfma_gemm(const __hip_bfloat16* __restrict__ Xb,
            const __hip_bfloat16* __restrict__ Wb,
            __hip_bfloat16* __restrict__ Pb) {
  const int lane = threadIdx.x & 63;
  const int w = threadIdx.x >> 6;  // wave id -> n tile
  const int m0 = blockIdx.x * 64;
  const int n0 = w * 64;
  const int lr = lane & 15;
  const int lk = lane >> 4;

  const ushort* X = reinterpret_cast<const ushort*>(Xb);
  const ushort* W = reinterpret_cast<const ushort*>(Wb);

  bf16x8 bfr[4][2];
#pragma unroll
  for (int ni = 0; ni < 4; ++ni)
#pragma unroll
    for (int kk = 0; kk < 2; ++kk) {
      int j = n0 + ni * 16 + lr;
      bfr[ni][kk] = *reinterpret_cast<const bf16x8*>(W + (size_t)j * 64 + kk * 32 + lk * 8);
    }

  bf16x8 afr[4][2];
#pragma unroll
  for (int mi = 0; mi < 4; ++mi)
#pragma unroll
    for (int kk = 0; kk < 2; ++kk) {
      int r = m0 + mi * 16 + lr;
      if (r >= NN) r = NN - 1;  // clamp; results discarded by store guard
      afr[mi][kk] = *reinterpret_cast<const bf16x8*>(X + (size_t)r * 64 + kk * 32 + lk * 8);
    }

  f32x4 acc[4][4] = {};
#pragma unroll
  for (int mi = 0; mi < 4; ++mi)
#pragma unroll
    for (int ni = 0; ni < 4; ++ni)
#pragma unroll
      for (int kk = 0; kk < 2; ++kk)
        acc[mi][ni] = __builtin_amdgcn_mfma_f32_16x16x32_bf16(
            afr[mi][kk], bfr[ni][kk], acc[mi][ni], 0, 0, 0);

#pragma unroll
  for (int mi = 0; mi < 4; ++mi) {
#pragma unroll
    for (int i = 0; i < 4; ++i) {
      int r = m0 + mi * 16 + lk * 4 + i;
      if (r < NN) {
#pragma unroll
        for (int ni = 0; ni < 4; ++ni) {
          int j = n0 + ni * 16 + lr;
          Pb[(size_t)r * JDIM + j] = __float2bfloat16(acc[mi][ni][i]);
        }
      }
    }
  }
}

// ---------------------------------------------------------------------------
// lane = CSR position: a[k][h] = exp(l_h) / sum * inv_count[dst].
// q prescaled by log2e; no max-sub (logits bounded ~|5|, exp2 range huge).
__global__ void k_attn(const int2* __restrict__ csr2, const float* __restrict__ q,
                       const float* __restrict__ cvec, const float* __restrict__ inv,
                       float* __restrict__ a) {
  int k = blockIdx.x * blockDim.x + threadIdx.x;
  if (k >= NE) return;
  int2 cd = csr2[k];
  int d = cd.x, s = cd.y;

  const float4* q4 = reinterpret_cast<const float4*>(q);
  const float4* c4 = reinterpret_cast<const float4*>(cvec);
  float4 qd0 = q4[2 * d], qd1 = q4[2 * d + 1];
  float4 qs0 = q4[2 * s], qs1 = q4[2 * s + 1];
  float4 c0 = c4[0], c1 = c4[1];

  float e[8];
  e[0] = __builtin_amdgcn_exp2f(qd0.x - qs0.x + c0.x * L2E);
  e[1] = __builtin_amdgcn_exp2f(qd0.y - qs0.y + c0.y * L2E);
  e[2] = __builtin_amdgcn_exp2f(qd0.z - qs0.z + c0.z * L2E);
  e[3] = __builtin_amdgcn_exp2f(qd0.w - qs0.w + c0.w * L2E);
  e[4] = __builtin_amdgcn_exp2f(qd1.x - qs1.x + c1.x * L2E);
  e[5] = __builtin_amdgcn_exp2f(qd1.y - qs1.y + c1.y * L2E);
  e[6] = __builtin_amdgcn_exp2f(qd1.z - qs1.z + c1.z * L2E);
  e[7] = __builtin_amdgcn_exp2f(qd1.w - qs1.w + c1.w * L2E);

  float sum = ((e[0] + e[1]) + (e[2] + e[3])) + ((e[4] + e[5]) + (e[6] + e[7]));
  float r = __builtin_amdgcn_rcpf(sum) * inv[d];

  float4 a0 = make_float4(e[0] * r, e[1] * r, e[2] * r, e[3] * r);
  float4 a1 = make_float4(e[4] * r, e[5] * r, e[6] * r, e[7] * r);
  reinterpret_cast<float4*>(a)[2 * (size_t)k] = a0;
  reinterpret_cast<float4*>(a)[2 * (size_t)k + 1] = a1;
}

// ---------------------------------------------------------------------------
// wave = src node (NPW=1) / half-wave = src node (NPW=2). P row in registers,
// per edge: 2 uniform float4 loads of a, 8 FMA, one 4B atomic per lane.
template <int COUT>
__global__ void k_agg(const int* __restrict__ base, const int* __restrict__ endp,
                      const int2* __restrict__ csr2, const float* __restrict__ a,
                      const __hip_bfloat16* __restrict__ Pb, float* __restrict__ agg) {
  constexpr int NPW = 64 / COUT;  // nodes per wave
  const int lane = threadIdx.x & 63;
  const long wid = ((long)blockIdx.x * blockDim.x + threadIdx.x) >> 6;
  const int n = (int)(wid * NPW + (NPW == 1 ? 0 : (lane >> 5)));
  if (n >= NN) return;
  const int o = lane & (COUT - 1);

  const ushort* P = reinterpret_cast<const ushort*>(Pb);
  float p[NH];
#pragma unroll
  for (int h = 0; h < NH; ++h) p[h] = b2f(P[(size_t)n * (NH * COUT) + h * COUT + o]);

  const float4* A4 = reinterpret_cast<const float4*>(a);
  for (int k = base[n], k1 = endp[n]; k < k1; ++k) {
    int d = csr2[k].x;
    if constexpr (NPW == 1) d = __builtin_amdgcn_readfirstlane(d);
    float4 a0 = A4[2 * (size_t)k];
    float4 a1 = A4[2 * (size_t)k + 1];
    float acc = 0.f;
    acc = fmaf(a0.x, p[0], acc);
    acc = fmaf(a0.y, p[1], acc);
    acc = fmaf(a0.z, p[2], acc);
    acc = fmaf(a0.w, p[3], acc);
    acc = fmaf(a1.x, p[4], acc);
    acc = fmaf(a1.y, p[5], acc);
    acc = fmaf(a1.z, p[6], acc);
    acc = fmaf(a1.w, p[7], acc);
    atomicAdd(&agg[(size_t)d * COUT + o], acc);
  }
}

// ---------------------------------------------------------------------------
// y = relu(agg + selfloop + b); selfloop = inv[n] * softmax(c) . P[n]-row.
// also accumulate per-channel sum/sumsq into stats.
__global__ void k_finalize_relu(const float* __restrict__ agg, const float* __restrict__ inv,
                                const float* __restrict__ b, const __hip_bfloat16* __restrict__ Pb,
                                const float* __restrict__ cvec,
                                float* __restrict__ y, float* __restrict__ stats) {
  __shared__ float ssum[64], ssq[64];
  const int t = threadIdx.x;
  if (t < 64) { ssum[t] = 0.f; ssq[t] = 0.f; }
  __syncthreads();

  // self-loop softmax weights (wave-uniform, cheap)
  float wc[8], wsum = 0.f;
#pragma unroll
  for (int h = 0; h < 8; ++h) { wc[h] = __builtin_amdgcn_exp2f(cvec[h] * L2E); wsum += wc[h]; }
  const float rs = __builtin_amdgcn_rcpf(wsum);

  const ushort* P = reinterpret_cast<const ushort*>(Pb);
  const int o = t & 63;
  const float bo = b[o];
  float lsum = 0.f, lsq = 0.f;
  for (long idx = (long)blockIdx.x * blockDim.x + threadIdx.x; idx < (long)NN * 64;
       idx += (long)gridDim.x * blockDim.x) {
    int n = (int)(idx >> 6);
    float sl = 0.f;
#pragma unroll
    for (int h = 0; h < 8; ++h) sl = fmaf(wc[h], b2f(P[(size_t)n * 512 + h * 64 + o]), sl);
    float v = fmaf(sl, rs * inv[n], agg[idx]) + bo;
    v = fmaxf(v, 0.f);
    y[idx] = v;
    lsum += v;
    lsq = fmaf(v, v, lsq);
  }
  atomicAdd(&ssum[o], lsum);
  atomicAdd(&ssq[o], lsq);
  __syncthreads();
  if (t < 64) {
    atomicAdd(&stats[t], ssum[t]);
    atomicAdd(&stats[64 + t], ssq[t]);
  }
}

// BN: writes h (fp32, for next layer's q) and hb (bf16, for MFMA)
__global__ void k_bn(const float* __restrict__ y, const float* __restrict__ stats,
                     const float* __restrict__ g, const float* __restrict__ be,
                     float* __restrict__ h, __hip_bfloat16* __restrict__ hb) {
  long idx = (long)blockIdx.x * blockDim.x + threadIdx.x;
  if (idx >= (long)NN * 64) return;
  int o = (int)(idx & 63);
  float m = stats[o] * (1.0f / NN);
  float v = stats[64 + o] * (1.0f / NN) - m * m;
  float r = fmaf(g[o] * rsqrtf(v + 1e-5f), y[idx] - m, be[o]);
  h[idx] = r;
  hb[idx] = __float2bfloat16(r);
}

// layer-3 epilogue: out = agg + selfloop + b   (COUT=32, P JDIM=256)
__global__ void k_final(const float* __restrict__ agg, const float* __restrict__ inv,
                        const float* __restrict__ b, const __hip_bfloat16* __restrict__ Pb,
                        const float* __restrict__ cvec, float* __restrict__ out) {
  long idx = (long)blockIdx.x * blockDim.x + threadIdx.x;
  if (idx >= (long)NN * 32) return;
  int n = (int)(idx >> 5);
  int o = (int)(idx & 31);

  float wc[8], wsum = 0.f;
#pragma unroll
  for (int h = 0; h < 8; ++h) { wc[h] = __builtin_amdgcn_exp2f(cvec[h] * L2E); wsum += wc[h]; }
  const float rs = __builtin_amdgcn_rcpf(wsum);

  const ushort* P = reinterpret_cast<const ushort*>(Pb);
  float sl = 0.f;
#pragma unroll
  for (int h = 0; h < 8; ++h) sl = fmaf(wc[h], b2f(P[(size_t)n * 256 + h * 32 + o]), sl);
  out[idx] = fmaf(sl, rs * inv[n], agg[idx]) + b[o];
}

// ---------------------------------------------------------------------------
extern "C" void kernel_launch(void* const* d_in, const int* in_sizes, int n_in,
                              void* d_out, int out_size, void* d_ws, size_t ws_size,
                              hipStream_t stream) {
  const float* x   = (const float*)d_in[0];
  const int*   src = (const int*)d_in[1];
  const int*   dst = src + NE;
  const float* W1 = (const float*)d_in[2];
  const float* U1 = (const float*)d_in[3];
  const float* c1 = (const float*)d_in[4];
  const float* b1 = (const float*)d_in[5];
  const float* g1 = (const float*)d_in[6];
  const float* be1 = (const float*)d_in[7];
  const float* W2 = (const float*)d_in[8];
  const float* U2 = (const float*)d_in[9];
  const float* c2 = (const float*)d_in[10];
  const float* b2 = (const float*)d_in[11];
  const float* g2 = (const float*)d_in[12];
  const float* be2 = (const float*)d_in[13];
  const float* W3 = (const float*)d_in[14];
  const float* U3 = (const float*)d_in[15];
  const float* c3 = (const float*)d_in[16];
  const float* b3 = (const float*)d_in[17];
  float* out = (float*)d_out;

  // workspace layout (float-equivalents; keep 16B alignment at every section)
  float* ws   = (float*)d_ws;
  float* inv  = ws;                        // N
  float* q    = inv + NN;                  // N*8
  float* agg  = q + (size_t)NN * 8;        // N*64
  float* h    = agg + (size_t)NN * 64;     // N*64
  float* stats = h + (size_t)NN * 64;      // 128
  float* a    = stats + 128;               // NE*8 (attention weights, CSR order)
  __hip_bfloat16* xb = (__hip_bfloat16*)(a + (size_t)NE * 8);   // N*64 bf16
  __hip_bfloat16* Wb = xb + (size_t)NN * 64;                    // 512*64 bf16
  __hip_bfloat16* Pb = Wb + 512 * 64;                           // N*512 bf16
  int* degout  = (int*)(Pb + (size_t)NN * 512);                 // N
  int* degin   = degout + NN;                                   // N
  int* basep   = degin + NN;                                    // N
  int* cursor  = basep + NN;                                    // N
  int2* csr2   = (int2*)(cursor + NN);                          // NE

  const int BLK = 256;
  dim3 b256(BLK);

  // ---- CSR build (once; reused by all 3 layers) ----
  hipMemsetAsync(degout, 0, (size_t)NN * 8, stream);  // degout + degin
  k_deg<<<dim3((NE + BLK - 1) / BLK), b256, 0, stream>>>(src, dst, degout, degin);
  k_inv<<<dim3((NN + BLK - 1) / BLK), b256, 0, stream>>>(degin, inv);
  k_scan<<<dim3(1), dim3(1024), 0, stream>>>(degout, basep, cursor);
  k_scatter<<<dim3((NE + BLK - 1) / BLK), b256, 0, stream>>>(src, dst, cursor, csr2);

  const int qgrid = (NN + BLK - 1) / BLK;
  const int mfma_grid = (NN + 63) / 64;
  const int attn_grid = (NE + BLK - 1) / BLK;
  const int agg_grid64 = (NN * 64 + BLK - 1) / BLK;       // 1 node per wave
  const int agg_grid32 = (NN * 32 + BLK - 1) / BLK;       // 2 nodes per wave
  const long xb4 = (long)NN * 64 / 4;
  const long wb4_512 = 512 * 64 / 4;

  // ---- layer 1: x -> h ----
  k_f2b<<<dim3((xb4 + BLK - 1) / BLK), b256, 0, stream>>>(x, xb, xb4);
  k_f2b<<<dim3((wb4_512 + BLK - 1) / BLK), b256, 0, stream>>>(W1, Wb, wb4_512);
  k_q<<<dim3(qgrid), b256, 0, stream>>>(x, U1, q);
  k_mfma_gemm<512><<<dim3(mfma_grid), dim3(512), 0, stream>>>(xb, Wb, Pb);
  k_attn<<<dim3(attn_grid), b256, 0, stream>>>(csr2, q, c1, inv, a);
  hipMemsetAsync(agg, 0, (size_t)NN * 64 * 4, stream);
  hipMemsetAsync(stats, 0, 128 * 4, stream);
  k_agg<64><<<dim3(agg_grid64), b256, 0, stream>>>(basep, cursor, csr2, a, Pb, agg);
  k_finalize_relu<<<dim3(1024), b256, 0, stream>>>(agg, inv, b1, Pb, c1, h, stats);
  k_bn<<<dim3(((size_t)NN * 64 + BLK - 1) / BLK), b256, 0, stream>>>(h, stats, g1, be1, h, xb);

  // ---- layer 2: h -> h ----
  k_f2b<<<dim3((wb4_512 + BLK - 1) / BLK), b256, 0, stream>>>(W2, Wb, wb4_512);
  k_q<<<dim3(qgrid), b256, 0, stream>>>(h, U2, q);
  k_mfma_gemm<512><<<dim3(mfma_grid), dim3(512), 0, stream>>>(xb, Wb, Pb);
  k_attn<<<dim3(attn_grid), b256, 0, stream>>>(csr2, q, c2, inv, a);
  hipMemsetAsync(agg, 0, (size_t)NN * 64 * 4, stream);
  hipMemsetAsync(stats, 0, 128 * 4, stream);
  k_agg<64><<<dim3(agg_grid64), b256, 0, stream>>>(basep, cursor, csr2, a, Pb, agg);
  k_finalize_relu<<<dim3(1024), b256, 0, stream>>>(agg, inv, b2, Pb, c2, h, stats);
  k_bn<<<dim3(((size_t)NN * 64 + BLK - 1) / BLK), b256, 0, stream>>>(h, stats, g2, be2, h, xb);

  // ---- layer 3: h -> out ----
  const long wb4_256 = 256 * 64 / 4;
  k_f2b<<<dim3((wb4_256 + BLK - 1) / BLK), b256, 0, stream>>>(W3, Wb, wb4_256);
  k_q<<<dim3(qgrid), b256, 0, stream>>>(h, U3, q);
  k_mfma_gemm<256><<<dim3(mfma_grid), dim3(256), 0, stream>>>(xb, Wb, Pb);
  k_attn<<<dim3(attn_grid), b256, 0, stream>>>(csr2, q, c3, inv, a);
  hipMemsetAsync(agg, 0, (size_t)NN * 32 * 4, stream);
  k_agg<32><<<dim3(agg_grid32), b256, 0, stream>>>(basep, cursor, csr2, a, Pb, agg);
  k_final<<<dim3(((size_t)NN * 32 + BLK - 1) / BLK), b256, 0, stream>>>(agg, inv, b3, Pb, c3, out);
}

// Round 6
// 718.285 us; speedup vs baseline: 1.2855x; 1.2855x over previous
//
#include <hip/hip_runtime.h>
#include <hip/hip_bf16.h>
#include <hip/hip_fp16.h>
#include <math.h>

constexpr int NN = 50000;   // nodes
constexpr int NE = 800000;  // edges (without self loops)
constexpr int NH = 8;       // heads
constexpr float L2E = 1.44269504f;  // log2(e)

typedef __attribute__((ext_vector_type(8))) short bf16x8;
typedef __attribute__((ext_vector_type(4))) float f32x4;

__device__ inline float b2f(unsigned short u) {
  union { unsigned int i; float f; } v;
  v.i = ((unsigned int)u) << 16;
  return v.f;
}

// ---------------------------------------------------------------------------
// degree histograms (real edges only; self-loop handled in epilogues)
__global__ void k_deg(const int* __restrict__ src, const int* __restrict__ dst,
                      int* __restrict__ degout, int* __restrict__ degin) {
  int i = blockIdx.x * blockDim.x + threadIdx.x;
  if (i < NE) {
    atomicAdd(&degout[src[i]], 1);
    atomicAdd(&degin[dst[i]], 1);
  }
}

__global__ void k_inv(const int* __restrict__ degin, float* __restrict__ inv) {
  int i = blockIdx.x * blockDim.x + threadIdx.x;
  if (i < NN) inv[i] = 1.0f / (float)(degin[i] + 1);
}

// single-block exclusive scan of degout -> base (also cursor = base)
__global__ void __launch_bounds__(1024) k_scan(const int* __restrict__ deg,
                                               int* __restrict__ base,
                                               int* __restrict__ cursor) {
  __shared__ int ls[1024];
  const int t = threadIdx.x;
  const int CHK = (NN + 1023) / 1024;  // 49
  const int start = t * CHK;
  int s = 0;
  for (int i = 0; i < CHK; ++i) {
    int idx = start + i;
    if (idx < NN) s += deg[idx];
  }
  ls[t] = s;
  __syncthreads();
  for (int off = 1; off < 1024; off <<= 1) {
    int v = (t >= off) ? ls[t - off] : 0;
    __syncthreads();
    ls[t] += v;
    __syncthreads();
  }
  int prefix = ls[t] - s;  // exclusive prefix for this chunk
  for (int i = 0; i < CHK; ++i) {
    int idx = start + i;
    if (idx < NN) {
      base[idx] = prefix;
      cursor[idx] = prefix;
      prefix += deg[idx];
    }
  }
}

// scatter: csr2[pos] = (dst, src), grouped by src. cursor[n] ends at range end.
__global__ void k_scatter(const int* __restrict__ src, const int* __restrict__ dst,
                          int* __restrict__ cursor, int2* __restrict__ csr2) {
  int e = blockIdx.x * blockDim.x + threadIdx.x;
  if (e < NE) {
    int s = src[e];
    int pos = atomicAdd(&cursor[s], 1);
    csr2[pos] = make_int2(dst[e], s);
  }
}

// ---------------------------------------------------------------------------
// fp32 -> bf16 conversion, 4 elements/thread
__global__ void k_f2b(const float* __restrict__ in, __hip_bfloat16* __restrict__ out,
                      long n4) {
  long i = (long)blockIdx.x * blockDim.x + threadIdx.x;
  if (i >= n4) return;
  float4 v = reinterpret_cast<const float4*>(in)[i];
  ushort4 o;
  o.x = __hip_bfloat16_raw(__float2bfloat16(v.x)).x;
  o.y = __hip_bfloat16_raw(__float2bfloat16(v.y)).x;
  o.z = __hip_bfloat16_raw(__float2bfloat16(v.z)).x;
  o.w = __hip_bfloat16_raw(__float2bfloat16(v.w)).x;
  reinterpret_cast<ushort4*>(out)[i] = o;
}

// ---------------------------------------------------------------------------
// q[n,h] = log2(e) * sum_c X[n,c] * U[h,c]   (prescaled for raw v_exp_f32)
__global__ void k_q(const float* __restrict__ X, const float* __restrict__ U,
                    float* __restrict__ q) {
  int n = blockIdx.x * blockDim.x + threadIdx.x;
  if (n >= NN) return;
  float4 xr[16];
  const float4* X4 = reinterpret_cast<const float4*>(X) + (size_t)n * 16;
#pragma unroll
  for (int i = 0; i < 16; ++i) xr[i] = X4[i];
  const float4* U4 = reinterpret_cast<const float4*>(U);
#pragma unroll
  for (int h = 0; h < 8; ++h) {
    float a = 0.f;
#pragma unroll
    for (int i = 0; i < 16; ++i) {
      float4 u = U4[h * 16 + i];
      a = fmaf(xr[i].x, u.x, a);
      a = fmaf(xr[i].y, u.y, a);
      a = fmaf(xr[i].z, u.z, a);
      a = fmaf(xr[i].w, u.w, a);
    }
    q[(size_t)n * 8 + h] = a * L2E;
  }
}

// ---------------------------------------------------------------------------
// P[n, j] = sum_c Xb[n,c] * Wb[j,c]  via MFMA bf16 (K=64 -> 2 k-steps of 32)
template <int JDIM>
__global__ void __launch_bounds__(JDIM / 64 * 64)
k_mfma_gemm(const __hip_bfloat16* __restrict__ Xb,
            const __hip_bfloat16* __restrict__ Wb,
            __hip_bfloat16* __restrict__ Pb) {
  const int lane = threadIdx.x & 63;
  const int w = threadIdx.x >> 6;  // wave id -> n tile
  const int m0 = blockIdx.x * 64;
  const int n0 = w * 64;
  const int lr = lane & 15;
  const int lk = lane >> 4;

  const ushort* X = reinterpret_cast<const ushort*>(Xb);
  const ushort* W = reinterpret_cast<const ushort*>(Wb);

  bf16x8 bfr[4][2];
#pragma unroll
  for (int ni = 0; ni < 4; ++ni)
#pragma unroll
    for (int kk = 0; kk < 2; ++kk) {
      int j = n0 + ni * 16 + lr;
      bfr[ni][kk] = *reinterpret_cast<const bf16x8*>(W + (size_t)j * 64 + kk * 32 + lk * 8);
    }

  bf16x8 afr[4][2];
#pragma unroll
  for (int mi = 0; mi < 4; ++mi)
#pragma unroll
    for (int kk = 0; kk < 2; ++kk) {
      int r = m0 + mi * 16 + lr;
      if (r >= NN) r = NN - 1;  // clamp; results discarded by store guard
      afr[mi][kk] = *reinterpret_cast<const bf16x8*>(X + (size_t)r * 64 + kk * 32 + lk * 8);
    }

  f32x4 acc[4][4] = {};
#pragma unroll
  for (int mi = 0; mi < 4; ++mi)
#pragma unroll
    for (int ni = 0; ni < 4; ++ni)
#pragma unroll
      for (int kk = 0; kk < 2; ++kk)
        acc[mi][ni] = __builtin_amdgcn_mfma_f32_16x16x32_bf16(
            afr[mi][kk], bfr[ni][kk], acc[mi][ni], 0, 0, 0);

#pragma unroll
  for (int mi = 0; mi < 4; ++mi) {
#pragma unroll
    for (int i = 0; i < 4; ++i) {
      int r = m0 + mi * 16 + lk * 4 + i;
      if (r < NN) {
#pragma unroll
        for (int ni = 0; ni < 4; ++ni) {
          int j = n0 + ni * 16 + lr;
          Pb[(size_t)r * JDIM + j] = __float2bfloat16(acc[mi][ni][i]);
        }
      }
    }
  }
}

// ---------------------------------------------------------------------------
// lane = CSR position: a[k][h] = exp(l_h) / sum * inv_count[dst].
__global__ void k_attn(const int2* __restrict__ csr2, const float* __restrict__ q,
                       const float* __restrict__ cvec, const float* __restrict__ inv,
                       float* __restrict__ a) {
  int k = blockIdx.x * blockDim.x + threadIdx.x;
  if (k >= NE) return;
  int2 cd = csr2[k];
  int d = cd.x, s = cd.y;

  const float4* q4 = reinterpret_cast<const float4*>(q);
  const float4* c4 = reinterpret_cast<const float4*>(cvec);
  float4 qd0 = q4[2 * d], qd1 = q4[2 * d + 1];
  float4 qs0 = q4[2 * s], qs1 = q4[2 * s + 1];
  float4 c0 = c4[0], c1 = c4[1];

  float e[8];
  e[0] = __builtin_amdgcn_exp2f(qd0.x - qs0.x + c0.x * L2E);
  e[1] = __builtin_amdgcn_exp2f(qd0.y - qs0.y + c0.y * L2E);
  e[2] = __builtin_amdgcn_exp2f(qd0.z - qs0.z + c0.z * L2E);
  e[3] = __builtin_amdgcn_exp2f(qd0.w - qs0.w + c0.w * L2E);
  e[4] = __builtin_amdgcn_exp2f(qd1.x - qs1.x + c1.x * L2E);
  e[5] = __builtin_amdgcn_exp2f(qd1.y - qs1.y + c1.y * L2E);
  e[6] = __builtin_amdgcn_exp2f(qd1.z - qs1.z + c1.z * L2E);
  e[7] = __builtin_amdgcn_exp2f(qd1.w - qs1.w + c1.w * L2E);

  float sum = ((e[0] + e[1]) + (e[2] + e[3])) + ((e[4] + e[5]) + (e[6] + e[7]));
  float r = __builtin_amdgcn_rcpf(sum) * inv[d];

  float4 a0 = make_float4(e[0] * r, e[1] * r, e[2] * r, e[3] * r);
  float4 a1 = make_float4(e[4] * r, e[5] * r, e[6] * r, e[7] * r);
  reinterpret_cast<float4*>(a)[2 * (size_t)k] = a0;
  reinterpret_cast<float4*>(a)[2 * (size_t)k + 1] = a1;
}

// ---------------------------------------------------------------------------
// Aggregation with packed-f16 atomics: lane owns a CHANNEL PAIR.
// COUT=64: 32 lanes/node, 2 nodes/wave.  COUT=32: 16 lanes/node, 4 nodes/wave.
// Per edge: uniform 32B a-load, 16 FMAs, ONE pk_add_f16 atomic per lane.
template <int COUT>
__global__ void k_agg(const int* __restrict__ base, const int* __restrict__ endp,
                      const int2* __restrict__ csr2, const float* __restrict__ a,
                      const __hip_bfloat16* __restrict__ Pb, __half2* __restrict__ agg) {
  constexpr int LPN = COUT / 2;   // lanes per node (32 / 16)
  constexpr int NPW = 64 / LPN;   // nodes per wave (2 / 4)
  const int lane = threadIdx.x & 63;
  const long wid = ((long)blockIdx.x * blockDim.x + threadIdx.x) >> 6;
  const int n = (int)(wid * NPW + lane / LPN);
  if (n >= NN) return;
  const int l = lane % LPN;       // channel-pair index: channels 2l, 2l+1

  // P row pair-fragment -> registers (uint = 2 bf16, coalesced per sub-wave)
  const unsigned int* P32 = reinterpret_cast<const unsigned int*>(Pb);
  float p0[NH], p1[NH];
#pragma unroll
  for (int h = 0; h < NH; ++h) {
    unsigned int v = P32[(size_t)n * (NH * LPN) + h * LPN + l];
    p0[h] = b2f((unsigned short)(v & 0xffff));
    p1[h] = b2f((unsigned short)(v >> 16));
  }

  const float4* A4 = reinterpret_cast<const float4*>(a);
  for (int k = base[n], k1 = endp[n]; k < k1; ++k) {
    int d = csr2[k].x;
    float4 a0 = A4[2 * (size_t)k];
    float4 a1 = A4[2 * (size_t)k + 1];
    float s0 = 0.f, s1 = 0.f;
    s0 = fmaf(a0.x, p0[0], s0);  s1 = fmaf(a0.x, p1[0], s1);
    s0 = fmaf(a0.y, p0[1], s0);  s1 = fmaf(a0.y, p1[1], s1);
    s0 = fmaf(a0.z, p0[2], s0);  s1 = fmaf(a0.z, p1[2], s1);
    s0 = fmaf(a0.w, p0[3], s0);  s1 = fmaf(a0.w, p1[3], s1);
    s0 = fmaf(a1.x, p0[4], s0);  s1 = fmaf(a1.x, p1[4], s1);
    s0 = fmaf(a1.y, p0[5], s0);  s1 = fmaf(a1.y, p1[5], s1);
    s0 = fmaf(a1.z, p0[6], s0);  s1 = fmaf(a1.z, p1[6], s1);
    s0 = fmaf(a1.w, p0[7], s0);  s1 = fmaf(a1.w, p1[7], s1);
    unsafeAtomicAdd(&agg[(size_t)d * LPN + l], __floats2half2_rn(s0, s1));
  }
}

// ---------------------------------------------------------------------------
// y = relu(agg + selfloop + b); selfloop = inv[n] * softmax(c) . P[n]-row.
// also accumulate per-channel sum/sumsq into stats.
__global__ void k_finalize_relu(const __half* __restrict__ aggh, const float* __restrict__ inv,
                                const float* __restrict__ b, const __hip_bfloat16* __restrict__ Pb,
                                const float* __restrict__ cvec,
                                float* __restrict__ y, float* __restrict__ stats) {
  __shared__ float ssum[64], ssq[64];
  const int t = threadIdx.x;
  if (t < 64) { ssum[t] = 0.f; ssq[t] = 0.f; }
  __syncthreads();

  float wc[8], wsum = 0.f;
#pragma unroll
  for (int h = 0; h < 8; ++h) { wc[h] = __builtin_amdgcn_exp2f(cvec[h] * L2E); wsum += wc[h]; }
  const float rs = __builtin_amdgcn_rcpf(wsum);

  const ushort* P = reinterpret_cast<const ushort*>(Pb);
  const int o = t & 63;
  const float bo = b[o];
  float lsum = 0.f, lsq = 0.f;
  for (long idx = (long)blockIdx.x * blockDim.x + threadIdx.x; idx < (long)NN * 64;
       idx += (long)gridDim.x * blockDim.x) {
    int n = (int)(idx >> 6);
    float sl = 0.f;
#pragma unroll
    for (int h = 0; h < 8; ++h) sl = fmaf(wc[h], b2f(P[(size_t)n * 512 + h * 64 + o]), sl);
    float v = fmaf(sl, rs * inv[n], __half2float(aggh[idx])) + bo;
    v = fmaxf(v, 0.f);
    y[idx] = v;
    lsum += v;
    lsq = fmaf(v, v, lsq);
  }
  atomicAdd(&ssum[o], lsum);
  atomicAdd(&ssq[o], lsq);
  __syncthreads();
  if (t < 64) {
    atomicAdd(&stats[t], ssum[t]);
    atomicAdd(&stats[64 + t], ssq[t]);
  }
}

// BN: writes h (fp32, for next layer's q) and hb (bf16, for MFMA)
__global__ void k_bn(const float* __restrict__ y, const float* __restrict__ stats,
                     const float* __restrict__ g, const float* __restrict__ be,
                     float* __restrict__ h, __hip_bfloat16* __restrict__ hb) {
  long idx = (long)blockIdx.x * blockDim.x + threadIdx.x;
  if (idx >= (long)NN * 64) return;
  int o = (int)(idx & 63);
  float m = stats[o] * (1.0f / NN);
  float v = stats[64 + o] * (1.0f / NN) - m * m;
  float r = fmaf(g[o] * rsqrtf(v + 1e-5f), y[idx] - m, be[o]);
  h[idx] = r;
  hb[idx] = __float2bfloat16(r);
}

// layer-3 epilogue: out = agg + selfloop + b   (COUT=32, P JDIM=256)
__global__ void k_final(const __half* __restrict__ aggh, const float* __restrict__ inv,
                        const float* __restrict__ b, const __hip_bfloat16* __restrict__ Pb,
                        const float* __restrict__ cvec, float* __restrict__ out) {
  long idx = (long)blockIdx.x * blockDim.x + threadIdx.x;
  if (idx >= (long)NN * 32) return;
  int n = (int)(idx >> 5);
  int o = (int)(idx & 31);

  float wc[8], wsum = 0.f;
#pragma unroll
  for (int h = 0; h < 8; ++h) { wc[h] = __builtin_amdgcn_exp2f(cvec[h] * L2E); wsum += wc[h]; }
  const float rs = __builtin_amdgcn_rcpf(wsum);

  const ushort* P = reinterpret_cast<const ushort*>(Pb);
  float sl = 0.f;
#pragma unroll
  for (int h = 0; h < 8; ++h) sl = fmaf(wc[h], b2f(P[(size_t)n * 256 + h * 32 + o]), sl);
  out[idx] = fmaf(sl, rs * inv[n], __half2float(aggh[idx])) + b[o];
}

// ---------------------------------------------------------------------------
extern "C" void kernel_launch(void* const* d_in, const int* in_sizes, int n_in,
                              void* d_out, int out_size, void* d_ws, size_t ws_size,
                              hipStream_t stream) {
  const float* x   = (const float*)d_in[0];
  const int*   src = (const int*)d_in[1];
  const int*   dst = src + NE;
  const float* W1 = (const float*)d_in[2];
  const float* U1 = (const float*)d_in[3];
  const float* c1 = (const float*)d_in[4];
  const float* b1 = (const float*)d_in[5];
  const float* g1 = (const float*)d_in[6];
  const float* be1 = (const float*)d_in[7];
  const float* W2 = (const float*)d_in[8];
  const float* U2 = (const float*)d_in[9];
  const float* c2 = (const float*)d_in[10];
  const float* b2 = (const float*)d_in[11];
  const float* g2 = (const float*)d_in[12];
  const float* be2 = (const float*)d_in[13];
  const float* W3 = (const float*)d_in[14];
  const float* U3 = (const float*)d_in[15];
  const float* c3 = (const float*)d_in[16];
  const float* b3 = (const float*)d_in[17];
  float* out = (float*)d_out;

  // workspace layout (float-equivalents; keep 16B alignment at every section)
  float* ws   = (float*)d_ws;
  float* inv  = ws;                        // N
  float* q    = inv + NN;                  // N*8
  float* aggf = q + (size_t)NN * 8;        // N*32 floats = N*64 halfs
  float* h    = aggf + (size_t)NN * 32;    // N*64
  float* stats = h + (size_t)NN * 64;      // 128
  float* a    = stats + 128;               // NE*8 (attention weights, CSR order)
  __hip_bfloat16* xb = (__hip_bfloat16*)(a + (size_t)NE * 8);   // N*64 bf16
  __hip_bfloat16* Wb = xb + (size_t)NN * 64;                    // 512*64 bf16
  __hip_bfloat16* Pb = Wb + 512 * 64;                           // N*512 bf16
  int* degout  = (int*)(Pb + (size_t)NN * 512);                 // N
  int* degin   = degout + NN;                                   // N
  int* basep   = degin + NN;                                    // N
  int* cursor  = basep + NN;                                    // N
  int2* csr2   = (int2*)(cursor + NN);                          // NE
  __half2* agg2 = (__half2*)aggf;
  __half*  aggh = (__half*)aggf;

  const int BLK = 256;
  dim3 b256(BLK);

  // ---- CSR build (once; reused by all 3 layers) ----
  hipMemsetAsync(degout, 0, (size_t)NN * 8, stream);  // degout + degin
  k_deg<<<dim3((NE + BLK - 1) / BLK), b256, 0, stream>>>(src, dst, degout, degin);
  k_inv<<<dim3((NN + BLK - 1) / BLK), b256, 0, stream>>>(degin, inv);
  k_scan<<<dim3(1), dim3(1024), 0, stream>>>(degout, basep, cursor);
  k_scatter<<<dim3((NE + BLK - 1) / BLK), b256, 0, stream>>>(src, dst, cursor, csr2);

  const int qgrid = (NN + BLK - 1) / BLK;
  const int mfma_grid = (NN + 63) / 64;
  const int attn_grid = (NE + BLK - 1) / BLK;
  const int agg_grid64 = (((NN + 1) / 2) * 64 + BLK - 1) / BLK;  // 2 nodes/wave
  const int agg_grid32 = (((NN + 3) / 4) * 64 + BLK - 1) / BLK;  // 4 nodes/wave
  const long xb4 = (long)NN * 64 / 4;
  const long wb4_512 = 512 * 64 / 4;

  // ---- layer 1: x -> h ----
  k_f2b<<<dim3((xb4 + BLK - 1) / BLK), b256, 0, stream>>>(x, xb, xb4);
  k_f2b<<<dim3((wb4_512 + BLK - 1) / BLK), b256, 0, stream>>>(W1, Wb, wb4_512);
  k_q<<<dim3(qgrid), b256, 0, stream>>>(x, U1, q);
  k_mfma_gemm<512><<<dim3(mfma_grid), dim3(512), 0, stream>>>(xb, Wb, Pb);
  k_attn<<<dim3(attn_grid), b256, 0, stream>>>(csr2, q, c1, inv, a);
  hipMemsetAsync(agg2, 0, (size_t)NN * 64 * 2, stream);
  hipMemsetAsync(stats, 0, 128 * 4, stream);
  k_agg<64><<<dim3(agg_grid64), b256, 0, stream>>>(basep, cursor, csr2, a, Pb, agg2);
  k_finalize_relu<<<dim3(1024), b256, 0, stream>>>(aggh, inv, b1, Pb, c1, h, stats);
  k_bn<<<dim3(((size_t)NN * 64 + BLK - 1) / BLK), b256, 0, stream>>>(h, stats, g1, be1, h, xb);

  // ---- layer 2: h -> h ----
  k_f2b<<<dim3((wb4_512 + BLK - 1) / BLK), b256, 0, stream>>>(W2, Wb, wb4_512);
  k_q<<<dim3(qgrid), b256, 0, stream>>>(h, U2, q);
  k_mfma_gemm<512><<<dim3(mfma_grid), dim3(512), 0, stream>>>(xb, Wb, Pb);
  k_attn<<<dim3(attn_grid), b256, 0, stream>>>(csr2, q, c2, inv, a);
  hipMemsetAsync(agg2, 0, (size_t)NN * 64 * 2, stream);
  hipMemsetAsync(stats, 0, 128 * 4, stream);
  k_agg<64><<<dim3(agg_grid64), b256, 0, stream>>>(basep, cursor, csr2, a, Pb, agg2);
  k_finalize_relu<<<dim3(1024), b256, 0, stream>>>(aggh, inv, b2, Pb, c2, h, stats);
  k_bn<<<dim3(((size_t)NN * 64 + BLK - 1) / BLK), b256, 0, stream>>>(h, stats, g2, be2, h, xb);

  // ---- layer 3: h -> out ----
  const long wb4_256 = 256 * 64 / 4;
  k_f2b<<<dim3((wb4_256 + BLK - 1) / BLK), b256, 0, stream>>>(W3, Wb, wb4_256);
  k_q<<<dim3(qgrid), b256, 0, stream>>>(h, U3, q);
  k_mfma_gemm<256><<<dim3(mfma_grid), dim3(256), 0, stream>>>(xb, Wb, Pb);
  k_attn<<<dim3(attn_grid), b256, 0, stream>>>(csr2, q, c3, inv, a);
  hipMemsetAsync(agg2, 0, (size_t)NN * 32 * 2, stream);
  k_agg<32><<<dim3(agg_grid32), b256, 0, stream>>>(basep, cursor, csr2, a, Pb, agg2);
  k_final<<<dim3(((size_t)NN * 32 + BLK - 1) / BLK), b256, 0, stream>>>(aggh, inv, b3, Pb, c3, out);
}

// Round 7
// 599.613 us; speedup vs baseline: 1.5399x; 1.1979x over previous
//
#include <hip/hip_runtime.h>
#include <hip/hip_bf16.h>
#include <hip/hip_fp16.h>
#include <math.h>

constexpr int NN = 50000;   // nodes
constexpr int NE = 800000;  // edges (without self loops)
constexpr int NH = 8;       // heads
constexpr float L2E = 1.44269504f;  // log2(e)
constexpr int SBLK = 256;
constexpr int SGRID = (NN + SBLK - 1) / SBLK;  // 196

typedef __attribute__((ext_vector_type(8))) short bf16x8;
typedef __attribute__((ext_vector_type(4))) float f32x4;

__device__ inline float b2f(unsigned short u) {
  union { unsigned int i; float f; } v;
  v.i = ((unsigned int)u) << 16;
  return v.f;
}

// ---------------------------------------------------------------------------
// degree histograms (real edges only; self-loop handled in epilogues)
__global__ void k_deg(const int* __restrict__ src, const int* __restrict__ dst,
                      int* __restrict__ degout, int* __restrict__ degin) {
  int i = blockIdx.x * blockDim.x + threadIdx.x;
  if (i < NE) {
    atomicAdd(&degout[src[i]], 1);
    atomicAdd(&degin[dst[i]], 1);
  }
}

__global__ void k_inv(const int* __restrict__ degin, float* __restrict__ inv) {
  int i = blockIdx.x * blockDim.x + threadIdx.x;
  if (i < NN) inv[i] = 1.0f / (float)(degin[i] + 1);
}

// ---- hierarchical exclusive scan (3 small kernels, full-device parallel) ----
__global__ void k_scan1(const int* __restrict__ deg, int* __restrict__ bsum) {
  int i = blockIdx.x * SBLK + threadIdx.x;
  int v = (i < NN) ? deg[i] : 0;
#pragma unroll
  for (int off = 32; off; off >>= 1) v += __shfl_down(v, off, 64);
  __shared__ int ws[SBLK / 64];
  if ((threadIdx.x & 63) == 0) ws[threadIdx.x >> 6] = v;
  __syncthreads();
  if (threadIdx.x == 0) {
    int s = 0;
#pragma unroll
    for (int w = 0; w < SBLK / 64; ++w) s += ws[w];
    bsum[blockIdx.x] = s;
  }
}

__global__ void k_scan2(int* __restrict__ bsum) {  // in-place exclusive scan of SGRID vals
  __shared__ int ls[256];
  int t = threadIdx.x;
  int v = (t < SGRID) ? bsum[t] : 0;
  ls[t] = v;
  __syncthreads();
  for (int off = 1; off < 256; off <<= 1) {
    int u = (t >= off) ? ls[t - off] : 0;
    __syncthreads();
    ls[t] += u;
    __syncthreads();
  }
  if (t < SGRID) bsum[t] = ls[t] - v;
}

__global__ void k_scan3(const int* __restrict__ deg, const int* __restrict__ bsum,
                        int* __restrict__ base, int* __restrict__ cursor) {
  __shared__ int ls[SBLK];
  int t = threadIdx.x;
  int i = blockIdx.x * SBLK + t;
  int v = (i < NN) ? deg[i] : 0;
  ls[t] = v;
  __syncthreads();
  for (int off = 1; off < SBLK; off <<= 1) {
    int u = (t >= off) ? ls[t - off] : 0;
    __syncthreads();
    ls[t] += u;
    __syncthreads();
  }
  int ex = ls[t] - v + bsum[blockIdx.x];
  if (i < NN) { base[i] = ex; cursor[i] = ex; }
}

// scatter: csr2[pos] = (dst, src), grouped by src. cursor[n] ends at range end.
__global__ void k_scatter(const int* __restrict__ src, const int* __restrict__ dst,
                          int* __restrict__ cursor, int2* __restrict__ csr2) {
  int e = blockIdx.x * blockDim.x + threadIdx.x;
  if (e < NE) {
    int s = src[e];
    int pos = atomicAdd(&cursor[s], 1);
    csr2[pos] = make_int2(dst[e], s);
  }
}

// ---------------------------------------------------------------------------
// fp32 -> bf16 conversion, 4 elements/thread
__global__ void k_f2b(const float* __restrict__ in, __hip_bfloat16* __restrict__ out,
                      long n4) {
  long i = (long)blockIdx.x * blockDim.x + threadIdx.x;
  if (i >= n4) return;
  float4 v = reinterpret_cast<const float4*>(in)[i];
  ushort4 o;
  o.x = __hip_bfloat16_raw(__float2bfloat16(v.x)).x;
  o.y = __hip_bfloat16_raw(__float2bfloat16(v.y)).x;
  o.z = __hip_bfloat16_raw(__float2bfloat16(v.z)).x;
  o.w = __hip_bfloat16_raw(__float2bfloat16(v.w)).x;
  reinterpret_cast<ushort4*>(out)[i] = o;
}

// convert W1,W2,W3 in a single launch
__global__ void k_f2b3(const float* __restrict__ w1, const float* __restrict__ w2,
                       const float* __restrict__ w3, __hip_bfloat16* __restrict__ o1,
                       __hip_bfloat16* __restrict__ o2, __hip_bfloat16* __restrict__ o3) {
  int i = blockIdx.x * blockDim.x + threadIdx.x;  // float4 index
  const int n1 = 512 * 64 / 4, n2 = 512 * 64 / 4, n3 = 256 * 64 / 4;
  const float* in; __hip_bfloat16* out; int j = i;
  if (j < n1) { in = w1; out = o1; }
  else if ((j -= n1) < n2) { in = w2; out = o2; }
  else if ((j -= n2) < n3) { in = w3; out = o3; }
  else return;
  float4 v = reinterpret_cast<const float4*>(in)[j];
  ushort4 o;
  o.x = __hip_bfloat16_raw(__float2bfloat16(v.x)).x;
  o.y = __hip_bfloat16_raw(__float2bfloat16(v.y)).x;
  o.z = __hip_bfloat16_raw(__float2bfloat16(v.z)).x;
  o.w = __hip_bfloat16_raw(__float2bfloat16(v.w)).x;
  reinterpret_cast<ushort4*>(out)[j] = o;
}

// ---------------------------------------------------------------------------
// q[n,h] = log2(e) * sum_c X[n,c] * U[h,c]   (prescaled for raw v_exp_f32)
__global__ void k_q(const float* __restrict__ X, const float* __restrict__ U,
                    float* __restrict__ q) {
  int n = blockIdx.x * blockDim.x + threadIdx.x;
  if (n >= NN) return;
  float4 xr[16];
  const float4* X4 = reinterpret_cast<const float4*>(X) + (size_t)n * 16;
#pragma unroll
  for (int i = 0; i < 16; ++i) xr[i] = X4[i];
  const float4* U4 = reinterpret_cast<const float4*>(U);
#pragma unroll
  for (int h = 0; h < 8; ++h) {
    float a = 0.f;
#pragma unroll
    for (int i = 0; i < 16; ++i) {
      float4 u = U4[h * 16 + i];
      a = fmaf(xr[i].x, u.x, a);
      a = fmaf(xr[i].y, u.y, a);
      a = fmaf(xr[i].z, u.z, a);
      a = fmaf(xr[i].w, u.w, a);
    }
    q[(size_t)n * 8 + h] = a * L2E;
  }
}

// ---------------------------------------------------------------------------
// P[n, j] = sum_c Xb[n,c] * Wb[j,c]  via MFMA bf16 (K=64 -> 2 k-steps of 32)
template <int JDIM>
__global__ void __launch_bounds__(JDIM / 64 * 64)
k_mfma_gemm(const __hip_bfloat16* __restrict__ Xb,
            const __hip_bfloat16* __restrict__ Wb,
            __hip_bfloat16* __restrict__ Pb) {
  const int lane = threadIdx.x & 63;
  const int w = threadIdx.x >> 6;  // wave id -> n tile
  const int m0 = blockIdx.x * 64;
  const int n0 = w * 64;
  const int lr = lane & 15;
  const int lk = lane >> 4;

  const ushort* X = reinterpret_cast<const ushort*>(Xb);
  const ushort* W = reinterpret_cast<const ushort*>(Wb);

  bf16x8 bfr[4][2];
#pragma unroll
  for (int ni = 0; ni < 4; ++ni)
#pragma unroll
    for (int kk = 0; kk < 2; ++kk) {
      int j = n0 + ni * 16 + lr;
      bfr[ni][kk] = *reinterpret_cast<const bf16x8*>(W + (size_t)j * 64 + kk * 32 + lk * 8);
    }

  bf16x8 afr[4][2];
#pragma unroll
  for (int mi = 0; mi < 4; ++mi)
#pragma unroll
    for (int kk = 0; kk < 2; ++kk) {
      int r = m0 + mi * 16 + lr;
      if (r >= NN) r = NN - 1;  // clamp; results discarded by store guard
      afr[mi][kk] = *reinterpret_cast<const bf16x8*>(X + (size_t)r * 64 + kk * 32 + lk * 8);
    }

  f32x4 acc[4][4] = {};
#pragma unroll
  for (int mi = 0; mi < 4; ++mi)
#pragma unroll
    for (int ni = 0; ni < 4; ++ni)
#pragma unroll
      for (int kk = 0; kk < 2; ++kk)
        acc[mi][ni] = __builtin_amdgcn_mfma_f32_16x16x32_bf16(
            afr[mi][kk], bfr[ni][kk], acc[mi][ni], 0, 0, 0);

#pragma unroll
  for (int mi = 0; mi < 4; ++mi) {
#pragma unroll
    for (int i = 0; i < 4; ++i) {
      int r = m0 + mi * 16 + lk * 4 + i;
      if (r < NN) {
#pragma unroll
        for (int ni = 0; ni < 4; ++ni) {
          int j = n0 + ni * 16 + lr;
          Pb[(size_t)r * JDIM + j] = __float2bfloat16(acc[mi][ni][i]);
        }
      }
    }
  }
}

// ---------------------------------------------------------------------------
// lane = CSR position: a[k][h] = exp(l_h) / sum * inv_count[dst].
__global__ void k_attn(const int2* __restrict__ csr2, const float* __restrict__ q,
                       const float* __restrict__ cvec, const float* __restrict__ inv,
                       float* __restrict__ a) {
  int k = blockIdx.x * blockDim.x + threadIdx.x;
  if (k >= NE) return;
  int2 cd = csr2[k];
  int d = cd.x, s = cd.y;

  const float4* q4 = reinterpret_cast<const float4*>(q);
  const float4* c4 = reinterpret_cast<const float4*>(cvec);
  float4 qd0 = q4[2 * d], qd1 = q4[2 * d + 1];
  float4 qs0 = q4[2 * s], qs1 = q4[2 * s + 1];
  float4 c0 = c4[0], c1 = c4[1];

  float e[8];
  e[0] = __builtin_amdgcn_exp2f(qd0.x - qs0.x + c0.x * L2E);
  e[1] = __builtin_amdgcn_exp2f(qd0.y - qs0.y + c0.y * L2E);
  e[2] = __builtin_amdgcn_exp2f(qd0.z - qs0.z + c0.z * L2E);
  e[3] = __builtin_amdgcn_exp2f(qd0.w - qs0.w + c0.w * L2E);
  e[4] = __builtin_amdgcn_exp2f(qd1.x - qs1.x + c1.x * L2E);
  e[5] = __builtin_amdgcn_exp2f(qd1.y - qs1.y + c1.y * L2E);
  e[6] = __builtin_amdgcn_exp2f(qd1.z - qs1.z + c1.z * L2E);
  e[7] = __builtin_amdgcn_exp2f(qd1.w - qs1.w + c1.w * L2E);

  float sum = ((e[0] + e[1]) + (e[2] + e[3])) + ((e[4] + e[5]) + (e[6] + e[7]));
  float r = __builtin_amdgcn_rcpf(sum) * inv[d];

  float4 a0 = make_float4(e[0] * r, e[1] * r, e[2] * r, e[3] * r);
  float4 a1 = make_float4(e[4] * r, e[5] * r, e[6] * r, e[7] * r);
  reinterpret_cast<float4*>(a)[2 * (size_t)k] = a0;
  reinterpret_cast<float4*>(a)[2 * (size_t)k + 1] = a1;
}

// ---------------------------------------------------------------------------
// Aggregation with packed-f16 atomics: lane owns a CHANNEL PAIR.
template <int COUT>
__global__ void k_agg(const int* __restrict__ base, const int* __restrict__ endp,
                      const int2* __restrict__ csr2, const float* __restrict__ a,
                      const __hip_bfloat16* __restrict__ Pb, __half2* __restrict__ agg) {
  constexpr int LPN = COUT / 2;   // lanes per node (32 / 16)
  constexpr int NPW = 64 / LPN;   // nodes per wave (2 / 4)
  const int lane = threadIdx.x & 63;
  const long wid = ((long)blockIdx.x * blockDim.x + threadIdx.x) >> 6;
  const int n = (int)(wid * NPW + lane / LPN);
  if (n >= NN) return;
  const int l = lane % LPN;       // channel-pair index: channels 2l, 2l+1

  const unsigned int* P32 = reinterpret_cast<const unsigned int*>(Pb);
  float p0[NH], p1[NH];
#pragma unroll
  for (int h = 0; h < NH; ++h) {
    unsigned int v = P32[(size_t)n * (NH * LPN) + h * LPN + l];
    p0[h] = b2f((unsigned short)(v & 0xffff));
    p1[h] = b2f((unsigned short)(v >> 16));
  }

  const float4* A4 = reinterpret_cast<const float4*>(a);
  for (int k = base[n], k1 = endp[n]; k < k1; ++k) {
    int d = csr2[k].x;
    float4 a0 = A4[2 * (size_t)k];
    float4 a1 = A4[2 * (size_t)k + 1];
    float s0 = 0.f, s1 = 0.f;
    s0 = fmaf(a0.x, p0[0], s0);  s1 = fmaf(a0.x, p1[0], s1);
    s0 = fmaf(a0.y, p0[1], s0);  s1 = fmaf(a0.y, p1[1], s1);
    s0 = fmaf(a0.z, p0[2], s0);  s1 = fmaf(a0.z, p1[2], s1);
    s0 = fmaf(a0.w, p0[3], s0);  s1 = fmaf(a0.w, p1[3], s1);
    s0 = fmaf(a1.x, p0[4], s0);  s1 = fmaf(a1.x, p1[4], s1);
    s0 = fmaf(a1.y, p0[5], s0);  s1 = fmaf(a1.y, p1[5], s1);
    s0 = fmaf(a1.z, p0[6], s0);  s1 = fmaf(a1.z, p1[6], s1);
    s0 = fmaf(a1.w, p0[7], s0);  s1 = fmaf(a1.w, p1[7], s1);
    unsafeAtomicAdd(&agg[(size_t)d * LPN + l], __floats2half2_rn(s0, s1));
  }
}

// ---------------------------------------------------------------------------
// y = relu(agg + selfloop + b); selfloop = inv[n] * softmax(c) . P[n]-row.
__global__ void k_finalize_relu(const __half* __restrict__ aggh, const float* __restrict__ inv,
                                const float* __restrict__ b, const __hip_bfloat16* __restrict__ Pb,
                                const float* __restrict__ cvec,
                                float* __restrict__ y, float* __restrict__ stats) {
  __shared__ float ssum[64], ssq[64];
  const int t = threadIdx.x;
  if (t < 64) { ssum[t] = 0.f; ssq[t] = 0.f; }
  __syncthreads();

  float wc[8], wsum = 0.f;
#pragma unroll
  for (int h = 0; h < 8; ++h) { wc[h] = __builtin_amdgcn_exp2f(cvec[h] * L2E); wsum += wc[h]; }
  const float rs = __builtin_amdgcn_rcpf(wsum);

  const ushort* P = reinterpret_cast<const ushort*>(Pb);
  const int o = t & 63;
  const float bo = b[o];
  float lsum = 0.f, lsq = 0.f;
  for (long idx = (long)blockIdx.x * blockDim.x + threadIdx.x; idx < (long)NN * 64;
       idx += (long)gridDim.x * blockDim.x) {
    int n = (int)(idx >> 6);
    float sl = 0.f;
#pragma unroll
    for (int h = 0; h < 8; ++h) sl = fmaf(wc[h], b2f(P[(size_t)n * 512 + h * 64 + o]), sl);
    float v = fmaf(sl, rs * inv[n], __half2float(aggh[idx])) + bo;
    v = fmaxf(v, 0.f);
    y[idx] = v;
    lsum += v;
    lsq = fmaf(v, v, lsq);
  }
  atomicAdd(&ssum[o], lsum);
  atomicAdd(&ssq[o], lsq);
  __syncthreads();
  if (t < 64) {
    atomicAdd(&stats[t], ssum[t]);
    atomicAdd(&stats[64 + t], ssq[t]);
  }
}

// BN: writes h (fp32, for next layer's q) and hb (bf16, for MFMA)
__global__ void k_bn(const float* __restrict__ y, const float* __restrict__ stats,
                     const float* __restrict__ g, const float* __restrict__ be,
                     float* __restrict__ h, __hip_bfloat16* __restrict__ hb) {
  long idx = (long)blockIdx.x * blockDim.x + threadIdx.x;
  if (idx >= (long)NN * 64) return;
  int o = (int)(idx & 63);
  float m = stats[o] * (1.0f / NN);
  float v = stats[64 + o] * (1.0f / NN) - m * m;
  float r = fmaf(g[o] * rsqrtf(v + 1e-5f), y[idx] - m, be[o]);
  h[idx] = r;
  hb[idx] = __float2bfloat16(r);
}

// layer-3 epilogue: out = agg + selfloop + b   (COUT=32, P JDIM=256)
__global__ void k_final(const __half* __restrict__ aggh, const float* __restrict__ inv,
                        const float* __restrict__ b, const __hip_bfloat16* __restrict__ Pb,
                        const float* __restrict__ cvec, float* __restrict__ out) {
  long idx = (long)blockIdx.x * blockDim.x + threadIdx.x;
  if (idx >= (long)NN * 32) return;
  int n = (int)(idx >> 5);
  int o = (int)(idx & 31);

  float wc[8], wsum = 0.f;
#pragma unroll
  for (int h = 0; h < 8; ++h) { wc[h] = __builtin_amdgcn_exp2f(cvec[h] * L2E); wsum += wc[h]; }
  const float rs = __builtin_amdgcn_rcpf(wsum);

  const ushort* P = reinterpret_cast<const ushort*>(Pb);
  float sl = 0.f;
#pragma unroll
  for (int h = 0; h < 8; ++h) sl = fmaf(wc[h], b2f(P[(size_t)n * 256 + h * 32 + o]), sl);
  out[idx] = fmaf(sl, rs * inv[n], __half2float(aggh[idx])) + b[o];
}

// ---------------------------------------------------------------------------
extern "C" void kernel_launch(void* const* d_in, const int* in_sizes, int n_in,
                              void* d_out, int out_size, void* d_ws, size_t ws_size,
                              hipStream_t stream) {
  const float* x   = (const float*)d_in[0];
  const int*   src = (const int*)d_in[1];
  const int*   dst = src + NE;
  const float* W1 = (const float*)d_in[2];
  const float* U1 = (const float*)d_in[3];
  const float* c1 = (const float*)d_in[4];
  const float* b1 = (const float*)d_in[5];
  const float* g1 = (const float*)d_in[6];
  const float* be1 = (const float*)d_in[7];
  const float* W2 = (const float*)d_in[8];
  const float* U2 = (const float*)d_in[9];
  const float* c2 = (const float*)d_in[10];
  const float* b2 = (const float*)d_in[11];
  const float* g2 = (const float*)d_in[12];
  const float* be2 = (const float*)d_in[13];
  const float* W3 = (const float*)d_in[14];
  const float* U3 = (const float*)d_in[15];
  const float* c3 = (const float*)d_in[16];
  const float* b3 = (const float*)d_in[17];
  float* out = (float*)d_out;

  // workspace layout (float-equivalents; keep 16B alignment at every section)
  float* ws   = (float*)d_ws;
  float* inv  = ws;                        // N
  float* q    = inv + NN;                  // N*8
  float* aggf = q + (size_t)NN * 8;        // N*32 floats = N*64 halfs
  float* h    = aggf + (size_t)NN * 32;    // N*64
  float* stats = h + (size_t)NN * 64;      // 128
  float* a    = stats + 128;               // NE*8 (attention weights, CSR order)
  __hip_bfloat16* xb = (__hip_bfloat16*)(a + (size_t)NE * 8);   // N*64 bf16
  __hip_bfloat16* Wb1 = xb + (size_t)NN * 64;                   // 512*64 bf16
  __hip_bfloat16* Wb2 = Wb1 + 512 * 64;                         // 512*64 bf16
  __hip_bfloat16* Wb3 = Wb2 + 512 * 64;                         // 256*64 bf16
  __hip_bfloat16* Pb = Wb3 + 256 * 64;                          // N*512 bf16
  int* degout  = (int*)(Pb + (size_t)NN * 512);                 // N
  int* degin   = degout + NN;                                   // N
  int* basep   = degin + NN;                                    // N
  int* cursor  = basep + NN;                                    // N
  int* bsum    = cursor + NN;                                   // SGRID (196)
  int2* csr2   = (int2*)(bsum + 256);                           // NE
  __half2* agg2 = (__half2*)aggf;
  __half*  aggh = (__half*)aggf;

  const int BLK = 256;
  dim3 b256(BLK);

  // ---- CSR build (once; reused by all 3 layers) ----
  hipMemsetAsync(degout, 0, (size_t)NN * 8, stream);  // degout + degin
  k_deg<<<dim3((NE + BLK - 1) / BLK), b256, 0, stream>>>(src, dst, degout, degin);
  k_inv<<<dim3((NN + BLK - 1) / BLK), b256, 0, stream>>>(degin, inv);
  k_scan1<<<dim3(SGRID), dim3(SBLK), 0, stream>>>(degout, bsum);
  k_scan2<<<dim3(1), dim3(256), 0, stream>>>(bsum);
  k_scan3<<<dim3(SGRID), dim3(SBLK), 0, stream>>>(degout, bsum, basep, cursor);
  k_scatter<<<dim3((NE + BLK - 1) / BLK), b256, 0, stream>>>(src, dst, cursor, csr2);

  const int qgrid = (NN + BLK - 1) / BLK;
  const int mfma_grid = (NN + 63) / 64;
  const int attn_grid = (NE + BLK - 1) / BLK;
  const int agg_grid64 = (((NN + 1) / 2) * 64 + BLK - 1) / BLK;  // 2 nodes/wave
  const int agg_grid32 = (((NN + 3) / 4) * 64 + BLK - 1) / BLK;  // 4 nodes/wave
  const long xb4 = (long)NN * 64 / 4;
  const int w3grid = ((512 * 64 / 4) * 2 + (256 * 64 / 4) + BLK - 1) / BLK;

  // one-time conversions
  k_f2b<<<dim3((xb4 + BLK - 1) / BLK), b256, 0, stream>>>(x, xb, xb4);
  k_f2b3<<<dim3(w3grid), b256, 0, stream>>>(W1, W2, W3, Wb1, Wb2, Wb3);

  // ---- layer 1: x -> h ----
  k_q<<<dim3(qgrid), b256, 0, stream>>>(x, U1, q);
  k_mfma_gemm<512><<<dim3(mfma_grid), dim3(512), 0, stream>>>(xb, Wb1, Pb);
  k_attn<<<dim3(attn_grid), b256, 0, stream>>>(csr2, q, c1, inv, a);
  hipMemsetAsync(agg2, 0, (size_t)NN * 64 * 2, stream);
  hipMemsetAsync(stats, 0, 128 * 4, stream);
  k_agg<64><<<dim3(agg_grid64), b256, 0, stream>>>(basep, cursor, csr2, a, Pb, agg2);
  k_finalize_relu<<<dim3(1024), b256, 0, stream>>>(aggh, inv, b1, Pb, c1, h, stats);
  k_bn<<<dim3(((size_t)NN * 64 + BLK - 1) / BLK), b256, 0, stream>>>(h, stats, g1, be1, h, xb);

  // ---- layer 2: h -> h ----
  k_q<<<dim3(qgrid), b256, 0, stream>>>(h, U2, q);
  k_mfma_gemm<512><<<dim3(mfma_grid), dim3(512), 0, stream>>>(xb, Wb2, Pb);
  k_attn<<<dim3(attn_grid), b256, 0, stream>>>(csr2, q, c2, inv, a);
  hipMemsetAsync(agg2, 0, (size_t)NN * 64 * 2, stream);
  hipMemsetAsync(stats, 0, 128 * 4, stream);
  k_agg<64><<<dim3(agg_grid64), b256, 0, stream>>>(basep, cursor, csr2, a, Pb, agg2);
  k_finalize_relu<<<dim3(1024), b256, 0, stream>>>(aggh, inv, b2, Pb, c2, h, stats);
  k_bn<<<dim3(((size_t)NN * 64 + BLK - 1) / BLK), b256, 0, stream>>>(h, stats, g2, be2, h, xb);

  // ---- layer 3: h -> out ----
  k_q<<<dim3(qgrid), b256, 0, stream>>>(h, U3, q);
  k_mfma_gemm<256><<<dim3(mfma_grid), dim3(256), 0, stream>>>(xb, Wb3, Pb);
  k_attn<<<dim3(attn_grid), b256, 0, stream>>>(csr2, q, c3, inv, a);
  hipMemsetAsync(agg2, 0, (size_t)NN * 32 * 2, stream);
  k_agg<32><<<dim3(agg_grid32), b256, 0, stream>>>(basep, cursor, csr2, a, Pb, agg2);
  k_final<<<dim3(((size_t)NN * 32 + BLK - 1) / BLK), b256, 0, stream>>>(aggh, inv, b3, Pb, c3, out);
}